// Round 3
// baseline (15.516 us; speedup 1.0000x reference)
//
#include <hip/hip_runtime.h>

// CCNOT(c1=0, c2=1, t=2) on 12 qubits, batch 2048.
// out[b, j] = state[b, j ^ (1<<9)] iff bits 11 and 10 of j are set, else state[b, j].
// Pure permuted copy at 512-float granularity -> float4 stays aligned+coalesced.
//
// Structure: one block per row (2048 blocks x 256 threads = 8 blocks/CU,
// 32 waves/CU). Each thread: 4 independent float4 loads issued back-to-back,
// then 4 plain stores. R2->R3 single-variable change: dropped nontemporal
// stores — output (32 MiB) fits in L2/L3; write-back cache can absorb the
// store stream instead of forcing HBM drain inside the kernel.

#define DIM 4096
#define VEC4_PER_ROW (DIM / 4)  // 1024

typedef float f32x4 __attribute__((ext_vector_type(4)));

__global__ __launch_bounds__(256) void ccnot_permute_kernel(
    const f32x4* __restrict__ in, f32x4* __restrict__ out) {
    const int r = blockIdx.x;                       // row = batch index
    const f32x4* rin = in + r * VEC4_PER_ROW;
    f32x4* rout = out + r * VEC4_PER_ROW;
    const int tid = threadIdx.x;

    f32x4 vals[4];
#pragma unroll
    for (int k = 0; k < 4; ++k) {
        int v = k * 256 + tid;                      // float4 index within row, 0..1023
        int c = v << 2;                             // element column
        int both = ((c >> 11) & (c >> 10)) & 1;     // controls: bits 11 & 10
        int src_c = c ^ (both << 9);                // target: bit 9
        vals[k] = rin[src_c >> 2];
    }
#pragma unroll
    for (int k = 0; k < 4; ++k) {
        int v = k * 256 + tid;
        rout[v] = vals[k];
    }
}

extern "C" void kernel_launch(void* const* d_in, const int* in_sizes, int n_in,
                              void* d_out, int out_size, void* d_ws, size_t ws_size,
                              hipStream_t stream) {
    const f32x4* state = (const f32x4*)d_in[0];
    f32x4* out = (f32x4*)d_out;
    dim3 block(256);
    dim3 grid(2048);  // one block per batch row
    ccnot_permute_kernel<<<grid, block, 0, stream>>>(state, out);
}

// Round 4
// 14.218 us; speedup vs baseline: 1.0913x; 1.0913x over previous
//
#include <hip/hip_runtime.h>

// CCNOT(c1=0, c2=1, t=2) on 12 qubits, batch 2048.
// out[b, j] = state[b, j ^ (1<<9)] iff bits 11 and 10 of j are set, else state[b, j].
// Pure permuted copy. In float4-index units: src_v = v ^ (1<<7) when column
// bits 11,10 set (1<<9 elements == 1<<7 float4s) — permutation never crosses
// a row, and bit7 swaps happen within a 2KiB-aligned span (coalesced).
//
// R4: nt stores (R2 win, +9%) + 8 float4/thread (1024 blocks x 256 thr,
// block = 2 rows): 8 independent loads in flight per thread before stores,
// half the workgroup count.

#define DIM 4096
#define TOTAL_VEC4 (2048 * DIM / 4)  // 2,097,152

typedef float f32x4 __attribute__((ext_vector_type(4)));

__global__ __launch_bounds__(256) void ccnot_permute_kernel(
    const f32x4* __restrict__ in, f32x4* __restrict__ out) {
    const int base = blockIdx.x * 2048 + threadIdx.x;  // block covers 2048 f4 = 2 rows

    f32x4 vals[8];
#pragma unroll
    for (int k = 0; k < 8; ++k) {
        int v = base + k * 256;                     // global float4 index
        int c = (v << 2) & (DIM - 1);               // element column within row
        int both = ((c >> 11) & (c >> 10)) & 1;     // controls: bits 11 & 10
        int src_v = v ^ (both << 7);                // target flip: bit 7 in f4 units
        vals[k] = in[src_v];
    }
#pragma unroll
    for (int k = 0; k < 8; ++k) {
        __builtin_nontemporal_store(vals[k], &out[base + k * 256]);
    }
}

extern "C" void kernel_launch(void* const* d_in, const int* in_sizes, int n_in,
                              void* d_out, int out_size, void* d_ws, size_t ws_size,
                              hipStream_t stream) {
    const f32x4* state = (const f32x4*)d_in[0];
    f32x4* out = (f32x4*)d_out;
    dim3 block(256);
    dim3 grid(1024);  // 2 rows per block
    ccnot_permute_kernel<<<grid, block, 0, stream>>>(state, out);
}